// Round 4
// baseline (95.922 us; speedup 1.0000x reference)
//
#include <hip/hip_runtime.h>
#include <hip/hip_bf16.h>
#include <math.h>

#define BATCH 4096
#define DIM 128
#define TWO_B 8192
// reps scaled by sqrt(2*log2(e)) so MFMA acc = 2*log2(e)*sim and
// exp(sim/T) = exp(2*sim) = exp2(acc) -- no epilogue multiply needed.
#define SCALE 1.69864374f

typedef __bf16 bf16;
typedef __bf16 bf16x8 __attribute__((ext_vector_type(8)));
typedef float floatx4 __attribute__((ext_vector_type(4)));

// Blocked, MFMA-fragment-native layout (unchanged from R3):
//   (row, k) -> repsL[(row>>4)*2048 + (k>>3)*128 + (row&15)*8 + (k&7)]
// One 16x16x32 fragment load = one coalesced 1KB global_load_dwordx4.

// Kernel 1: L2-normalize (and pre-scale) -> blocked bf16 reps; positives; zero out.
__global__ __launch_bounds__(256) void norm_kernel(const float* __restrict__ p1,
                                                   const float* __restrict__ p2,
                                                   bf16* __restrict__ repsL,
                                                   float* __restrict__ pos,
                                                   float* __restrict__ out) {
    int tid = threadIdx.x;
    int w = tid >> 6, l = tid & 63;
    int b = blockIdx.x * 4 + w;
    const float* r1 = p1 + (size_t)b * DIM;
    const float* r2 = p2 + (size_t)b * DIM;
    float x0 = r1[l], x1 = r1[l + 64];
    float y0 = r2[l], y1 = r2[l + 64];
    float s1 = x0 * x0 + x1 * x1;
    float s2 = y0 * y0 + y1 * y1;
    float s12 = x0 * y0 + x1 * y1;
    #pragma unroll
    for (int off = 32; off; off >>= 1) {
        s1  += __shfl_xor(s1, off);
        s2  += __shfl_xor(s2, off);
        s12 += __shfl_xor(s12, off);
    }
    float n1 = fmaxf(sqrtf(s1), 1e-12f);
    float n2 = fmaxf(sqrtf(s2), 1e-12f);
    float i1 = SCALE / n1;
    float i2 = SCALE / n2;

    int row1 = b, row2 = b + BATCH;
    size_t a1 = (size_t)(row1 >> 4) * 2048 + (row1 & 15) * 8;
    size_t a2 = (size_t)(row2 >> 4) * 2048 + (row2 & 15) * 8;
    int c0 = (l >> 3) * 128 + (l & 7);      // k = l
    int c1 = c0 + 8 * 128;                  // k = l + 64
    repsL[a1 + c0] = (bf16)(x0 * i1);
    repsL[a1 + c1] = (bf16)(x1 * i1);
    repsL[a2 + c0] = (bf16)(y0 * i2);
    repsL[a2 + c1] = (bf16)(y1 * i2);

    if (l == 0) {
        pos[b] = s12 / (n1 * n2);           // exact fp32 positive (unscaled)
        if (b == 0) out[0] = 0.0f;
    }
}

// strip s pairs TM=s (TN=s..63) with TM=63-s (TN=63-s..63): always 65 steps.
__device__ __forceinline__ void strip_coords(int s, int t, int& TM, int& TN) {
    if (t < 64 - s) { TM = s;      TN = s + t; }
    else            { TM = 63 - s; TN = (63 - s) + (t - (64 - s)); }
}

// Kernel 2: strip-persistent 128x128 block-steps. 4 waves (2x2 of 64x64).
// A-fragments register-resident across the chunk; B(t+1) prefetched before
// epilogue(t) so epilogue VALU hides all load latency. No LDS, no atomics:
// wave-tile (tm,tn), tm<=tn writes row-exp-sums to part[tn][rows(tm)] and
// (off-diag) col-exp-sums to part[tm][rows(tn)] -- each slot written once.
__global__ __launch_bounds__(256, 2) void sim_kernel(const bf16* __restrict__ repsL,
                                                     float* __restrict__ part) {
    int tid = threadIdx.x;
    int wid = tid >> 6, lane = tid & 63;
    int wm = wid >> 1, wn = wid & 1;
    int lr = lane & 15, q = lane >> 4;
    int s = blockIdx.y;                 // strip [0,32)
    int t0 = blockIdx.x * 5;            // 13 chunks x 5 = 65 steps exactly

    const char* base = (const char*)repsL;
    int lofs = q * 256 + lr * 16;

    int TM, TN;
    strip_coords(s, t0, TM, TN);

    bf16x8 af[16], bfr[16];             // [mi*4+ks], [ni*4+ks]
    {
        const char* ab = base + (2 * TM + wm) * 16384 + lofs;
        #pragma unroll
        for (int i = 0; i < 16; ++i)
            af[i] = *(const bf16x8*)(ab + (i >> 2) * 4096 + (i & 3) * 1024);
        const char* bb = base + (2 * TN + wn) * 16384 + lofs;
        #pragma unroll
        for (int i = 0; i < 16; ++i)
            bfr[i] = *(const bf16x8*)(bb + (i >> 2) * 4096 + (i & 3) * 1024);
    }

    #pragma unroll 1
    for (int t = t0; t < t0 + 5; ++t) {
        int tm = 2 * TM + wm, tn = 2 * TN + wn;
        bool diag = (tm == tn);
        bool skip = (TM == TN) && (wm == 1) && (wn == 0);   // mirror quadrant

        floatx4 acc[4][4] = {};
        #pragma unroll
        for (int ks = 0; ks < 4; ++ks)
            #pragma unroll
            for (int mi = 0; mi < 4; ++mi)
                #pragma unroll
                for (int ni = 0; ni < 4; ++ni)
                    acc[mi][ni] = __builtin_amdgcn_mfma_f32_16x16x32_bf16(
                        af[mi * 4 + ks], bfr[ni * 4 + ks], acc[mi][ni], 0, 0, 0);

        // prefetch next step's fragments (hidden under this step's epilogue)
        if (t + 1 < t0 + 5) {
            int TMn, TNn;
            strip_coords(s, t + 1, TMn, TNn);
            const char* bbn = base + (2 * TNn + wn) * 16384 + lofs;
            #pragma unroll
            for (int i = 0; i < 16; ++i)
                bfr[i] = *(const bf16x8*)(bbn + (i >> 2) * 4096 + (i & 3) * 1024);
            if (TMn != TM) {            // strip seam: reload A
                const char* abn = base + (2 * TMn + wm) * 16384 + lofs;
                #pragma unroll
                for (int i = 0; i < 16; ++i)
                    af[i] = *(const bf16x8*)(abn + (i >> 2) * 4096 + (i & 3) * 1024);
            }
            TM = TMn; TN = TNn;
        }

        // Epilogue. C/D layout: col = lr (+16 ni), row = q*4+reg (+16 mi).
        if (!skip) {
            int growb = tm * 64 + q * 4;
            int gcolb = tn * 64 + lr;
            float cs[4] = {0.0f, 0.0f, 0.0f, 0.0f};
            #pragma unroll
            for (int mi = 0; mi < 4; ++mi) {
                #pragma unroll
                for (int reg = 0; reg < 4; ++reg) {
                    float e0 = exp2f(acc[mi][0][reg]);
                    float e1 = exp2f(acc[mi][1][reg]);
                    float e2 = exp2f(acc[mi][2][reg]);
                    float e3 = exp2f(acc[mi][3][reg]);
                    if (diag) {                          // exact diagonal mask
                        int grow = growb + mi * 16 + reg;
                        if (grow == gcolb)      e0 = 0.0f;
                        if (grow == gcolb + 16) e1 = 0.0f;
                        if (grow == gcolb + 32) e2 = 0.0f;
                        if (grow == gcolb + 48) e3 = 0.0f;
                    }
                    cs[0] += e0; cs[1] += e1; cs[2] += e2; cs[3] += e3;
                    float sv = (e0 + e1) + (e2 + e3);
                    sv += __shfl_xor(sv, 1);
                    sv += __shfl_xor(sv, 2);
                    sv += __shfl_xor(sv, 4);
                    sv += __shfl_xor(sv, 8);
                    if (lr == 0)
                        part[(size_t)tn * TWO_B + growb + mi * 16 + reg] = sv;
                }
            }
            if (!diag) {
                #pragma unroll
                for (int ni = 0; ni < 4; ++ni) {
                    cs[ni] += __shfl_xor(cs[ni], 16);
                    cs[ni] += __shfl_xor(cs[ni], 32);
                }
                if (q == 0) {
                    #pragma unroll
                    for (int ni = 0; ni < 4; ++ni)
                        part[(size_t)tm * TWO_B + gcolb + ni * 16] = cs[ni];
                }
            }
        }
    }
}

// Kernel 3: denom[r] = sum_k part[k][r]; loss = mean(log(denom) - 2*pos).
__global__ __launch_bounds__(256) void reduce_kernel(const float* __restrict__ part,
                                                     const float* __restrict__ pos,
                                                     float* __restrict__ out) {
    int tid = threadIdx.x;
    int rr = blockIdx.x * 256 + tid;
    float s = 0.0f;
    #pragma unroll 8
    for (int k = 0; k < 128; ++k)
        s += part[(size_t)k * TWO_B + rr];
    float v = __logf(s) - 2.0f * pos[rr & (BATCH - 1)];
    #pragma unroll
    for (int off = 32; off; off >>= 1) v += __shfl_xor(v, off);
    __shared__ float sred[4];
    int lane = tid & 63, wid = tid >> 6;
    if (lane == 0) sred[wid] = v;
    __syncthreads();
    if (tid == 0)
        atomicAdd(out, (sred[0] + sred[1] + sred[2] + sred[3]) * (1.0f / TWO_B));
}

extern "C" void kernel_launch(void* const* d_in, const int* in_sizes, int n_in,
                              void* d_out, int out_size, void* d_ws, size_t ws_size,
                              hipStream_t stream) {
    const float* p1 = (const float*)d_in[0];
    const float* p2 = (const float*)d_in[1];
    float* out = (float*)d_out;

    char* ws = (char*)d_ws;
    bf16* repsL = (bf16*)ws;                                          // 2 MB
    float* pos = (float*)(ws + (size_t)TWO_B * DIM * sizeof(bf16));   // 16 KB
    float* part = pos + BATCH;                                        // 4 MB

    norm_kernel<<<BATCH / 4, 256, 0, stream>>>(p1, p2, repsL, pos, out);
    sim_kernel<<<dim3(13, 32), 256, 0, stream>>>(repsL, part);
    reduce_kernel<<<TWO_B / 256, 256, 0, stream>>>(part, pos, out);
}

// Round 5
// 94.355 us; speedup vs baseline: 1.0166x; 1.0166x over previous
//
#include <hip/hip_runtime.h>
#include <hip/hip_bf16.h>
#include <math.h>

#define BATCH 4096
#define DIM 128
#define TWO_B 8192
// reps scaled by sqrt(2*log2(e)) so MFMA acc = 2*log2(e)*sim and
// exp(sim/T) = exp(2*sim) = exp2(acc) -- bare v_exp_f32 in the epilogue.
#define SCALE 1.69864374f

typedef __bf16 bf16;
typedef __bf16 bf16x8 __attribute__((ext_vector_type(8)));
typedef float floatx4 __attribute__((ext_vector_type(4)));

// Blocked, MFMA-fragment-native layout:
//   (row, k) -> repsL[(row>>4)*2048 + (k>>3)*128 + (row&15)*8 + (k&7)]
// One 16x16x32 fragment load = one coalesced 1KB global_load_dwordx4.

// Kernel 1: L2-normalize (and pre-scale) -> blocked bf16 reps; positives; zero out.
__global__ __launch_bounds__(256) void norm_kernel(const float* __restrict__ p1,
                                                   const float* __restrict__ p2,
                                                   bf16* __restrict__ repsL,
                                                   float* __restrict__ pos,
                                                   float* __restrict__ out) {
    int tid = threadIdx.x;
    int w = tid >> 6, l = tid & 63;
    int b = blockIdx.x * 4 + w;
    const float* r1 = p1 + (size_t)b * DIM;
    const float* r2 = p2 + (size_t)b * DIM;
    float x0 = r1[l], x1 = r1[l + 64];
    float y0 = r2[l], y1 = r2[l + 64];
    float s1 = x0 * x0 + x1 * x1;
    float s2 = y0 * y0 + y1 * y1;
    float s12 = x0 * y0 + x1 * y1;
    #pragma unroll
    for (int off = 32; off; off >>= 1) {
        s1  += __shfl_xor(s1, off);
        s2  += __shfl_xor(s2, off);
        s12 += __shfl_xor(s12, off);
    }
    float n1 = fmaxf(sqrtf(s1), 1e-12f);
    float n2 = fmaxf(sqrtf(s2), 1e-12f);
    float i1 = SCALE / n1;
    float i2 = SCALE / n2;

    int row1 = b, row2 = b + BATCH;
    size_t a1 = (size_t)(row1 >> 4) * 2048 + (row1 & 15) * 8;
    size_t a2 = (size_t)(row2 >> 4) * 2048 + (row2 & 15) * 8;
    int c0 = (l >> 3) * 128 + (l & 7);      // k = l
    int c1 = c0 + 8 * 128;                  // k = l + 64
    repsL[a1 + c0] = (bf16)(x0 * i1);
    repsL[a1 + c1] = (bf16)(x1 * i1);
    repsL[a2 + c0] = (bf16)(y0 * i2);
    repsL[a2 + c1] = (bf16)(y1 * i2);

    if (l == 0) {
        pos[b] = s12 / (n1 * n2);           // exact fp32 positive (unscaled)
        if (b == 0) out[0] = 0.0f;
    }
}

// Kernel 2: one wave per unordered 64x64 tile pair (tm <= tn), 8256 pairs.
// Fragments for both tiles loaded once; TWO MFMA passes (D1 = sim[tm][tn],
// D2 = sim[tn][tm] = D1^T) so BOTH marginals come from the cheap column-sum
// pattern: in-lane accumulate over 16 values + 2 shfl -- no dependent
// per-value shuffle trees. No LDS, no atomics, no barriers.
// part[k][r] slot coverage for row r in block j: k<j from pair (k,j) pass-1,
// k>j from pair (j,k) pass-2, k==j from diag pair -- each written exactly once.
// 4 waves/block share tm (A-fragments L1-resident); grid (33,64), c>=129 idle.
__global__ __launch_bounds__(256, 2) void sim_kernel(const bf16* __restrict__ repsL,
                                                     float* __restrict__ part) {
    int tid = threadIdx.x;
    int wid = tid >> 6, lane = tid & 63;
    int lr = lane & 15, q = lane >> 4;
    int r = blockIdx.y;                  // [0,64)
    int c = blockIdx.x * 4 + wid;        // [0,132)
    if (c >= 129) return;
    int tm, tn;
    if (c < 128 - r) { tm = r; tn = r + c; }
    else             { tm = 127 - r; tn = tm + (c - (128 - r)); }
    bool diag = (tm == tn);

    const char* base = (const char*)repsL;
    int lofs = q * 256 + lr * 16;
    const char* ab = base + tm * 16384 + lofs;
    const char* bb = base + tn * 16384 + lofs;

    bf16x8 af[16], bfr[16];              // [mi*4 + ks] / [ni*4 + ks]
    #pragma unroll
    for (int i = 0; i < 16; ++i) {
        af[i]  = *(const bf16x8*)(ab + (i >> 2) * 4096 + (i & 3) * 1024);
        bfr[i] = *(const bf16x8*)(bb + (i >> 2) * 4096 + (i & 3) * 1024);
    }

    // ---- Pass 1: D1[m][n] = sim[tm*64+m][tn*64+n] ----
    floatx4 acc[4][4] = {};
    #pragma unroll
    for (int ks = 0; ks < 4; ++ks)
        #pragma unroll
        for (int mi = 0; mi < 4; ++mi)
            #pragma unroll
            for (int ni = 0; ni < 4; ++ni)
                acc[mi][ni] = __builtin_amdgcn_mfma_f32_16x16x32_bf16(
                    af[mi * 4 + ks], bfr[ni * 4 + ks], acc[mi][ni], 0, 0, 0);

    // col-sums over m (lane: col = lr+16ni, row = q*4+reg+16mi)
    {
        float cs[4] = {0.0f, 0.0f, 0.0f, 0.0f};
        #pragma unroll
        for (int mi = 0; mi < 4; ++mi)
            #pragma unroll
            for (int ni = 0; ni < 4; ++ni)
                #pragma unroll
                for (int reg = 0; reg < 4; ++reg) {
                    float e = exp2f(acc[mi][ni][reg]);
                    if (diag && mi == ni && (q * 4 + reg) == lr) e = 0.0f;
                    cs[ni] += e;
                }
        #pragma unroll
        for (int ni = 0; ni < 4; ++ni) {
            cs[ni] += __shfl_xor(cs[ni], 16);
            cs[ni] += __shfl_xor(cs[ni], 32);
        }
        if (q == 0) {
            #pragma unroll
            for (int ni = 0; ni < 4; ++ni)
                part[(size_t)tm * TWO_B + tn * 64 + 16 * ni + lr] = cs[ni];
        }
    }

    if (diag) return;

    // ---- Pass 2: D2[m][n] = sim[tn*64+m][tm*64+n] (operands swapped) ----
    #pragma unroll
    for (int mi = 0; mi < 4; ++mi)
        #pragma unroll
        for (int ni = 0; ni < 4; ++ni)
            acc[mi][ni] = (floatx4){0.0f, 0.0f, 0.0f, 0.0f};
    #pragma unroll
    for (int ks = 0; ks < 4; ++ks)
        #pragma unroll
        for (int mi = 0; mi < 4; ++mi)
            #pragma unroll
            for (int ni = 0; ni < 4; ++ni)
                acc[mi][ni] = __builtin_amdgcn_mfma_f32_16x16x32_bf16(
                    bfr[mi * 4 + ks], af[ni * 4 + ks], acc[mi][ni], 0, 0, 0);

    {
        float cs[4] = {0.0f, 0.0f, 0.0f, 0.0f};
        #pragma unroll
        for (int mi = 0; mi < 4; ++mi)
            #pragma unroll
            for (int ni = 0; ni < 4; ++ni)
                #pragma unroll
                for (int reg = 0; reg < 4; ++reg)
                    cs[ni] += exp2f(acc[mi][ni][reg]);
        #pragma unroll
        for (int ni = 0; ni < 4; ++ni) {
            cs[ni] += __shfl_xor(cs[ni], 16);
            cs[ni] += __shfl_xor(cs[ni], 32);
        }
        if (q == 0) {
            #pragma unroll
            for (int ni = 0; ni < 4; ++ni)
                part[(size_t)tn * TWO_B + tm * 64 + 16 * ni + lr] = cs[ni];
        }
    }
}

// Kernel 3: denom[r] = sum_k part[k][r]; loss = mean(log(denom) - 2*pos).
__global__ __launch_bounds__(256) void reduce_kernel(const float* __restrict__ part,
                                                     const float* __restrict__ pos,
                                                     float* __restrict__ out) {
    int tid = threadIdx.x;
    int rr = blockIdx.x * 256 + tid;
    float s = 0.0f;
    #pragma unroll 8
    for (int k = 0; k < 128; ++k)
        s += part[(size_t)k * TWO_B + rr];
    float v = __logf(s) - 2.0f * pos[rr & (BATCH - 1)];
    #pragma unroll
    for (int off = 32; off; off >>= 1) v += __shfl_xor(v, off);
    __shared__ float sred[4];
    int lane = tid & 63, wid = tid >> 6;
    if (lane == 0) sred[wid] = v;
    __syncthreads();
    if (tid == 0)
        atomicAdd(out, (sred[0] + sred[1] + sred[2] + sred[3]) * (1.0f / TWO_B));
}

extern "C" void kernel_launch(void* const* d_in, const int* in_sizes, int n_in,
                              void* d_out, int out_size, void* d_ws, size_t ws_size,
                              hipStream_t stream) {
    const float* p1 = (const float*)d_in[0];
    const float* p2 = (const float*)d_in[1];
    float* out = (float*)d_out;

    char* ws = (char*)d_ws;
    bf16* repsL = (bf16*)ws;                                          // 2 MB
    float* pos = (float*)(ws + (size_t)TWO_B * DIM * sizeof(bf16));   // 16 KB
    float* part = pos + BATCH;                                        // 4 MB

    norm_kernel<<<BATCH / 4, 256, 0, stream>>>(p1, p2, repsL, pos, out);
    sim_kernel<<<dim3(33, 64), 256, 0, stream>>>(repsL, part);
    reduce_kernel<<<TWO_B / 256, 256, 0, stream>>>(part, pos, out);
}

// Round 6
// 88.712 us; speedup vs baseline: 1.0813x; 1.0636x over previous
//
#include <hip/hip_runtime.h>
#include <hip/hip_bf16.h>
#include <math.h>

#define BATCH 4096
#define DIM 128
#define TWO_B 8192
// reps scaled by sqrt(2) so MFMA acc = 2*sim, and exp(sim/TEMP) = exp(acc)
// = __expf(acc) -> native v_mul(log2e) + v_exp_f32, no OCML range handling.
#define SCALE 1.41421356f

typedef __bf16 bf16;
typedef __bf16 bf16x8 __attribute__((ext_vector_type(8)));
typedef float floatx4 __attribute__((ext_vector_type(4)));

// Blocked, MFMA-fragment-native layout:
//   (row, k) -> repsL[(row>>4)*2048 + (k>>3)*128 + (row&15)*8 + (k&7)]
// One 16x16x32 fragment load = one coalesced 1KB global_load_dwordx4.

// Kernel 1: L2-normalize (pre-scaled by sqrt(2)) -> blocked bf16 reps; positives.
__global__ __launch_bounds__(256) void norm_kernel(const float* __restrict__ p1,
                                                   const float* __restrict__ p2,
                                                   bf16* __restrict__ repsL,
                                                   float* __restrict__ pos,
                                                   float* __restrict__ out) {
    int tid = threadIdx.x;
    int w = tid >> 6, l = tid & 63;
    int b = blockIdx.x * 4 + w;
    const float* r1 = p1 + (size_t)b * DIM;
    const float* r2 = p2 + (size_t)b * DIM;
    float x0 = r1[l], x1 = r1[l + 64];
    float y0 = r2[l], y1 = r2[l + 64];
    float s1 = x0 * x0 + x1 * x1;
    float s2 = y0 * y0 + y1 * y1;
    float s12 = x0 * y0 + x1 * y1;
    #pragma unroll
    for (int off = 32; off; off >>= 1) {
        s1  += __shfl_xor(s1, off);
        s2  += __shfl_xor(s2, off);
        s12 += __shfl_xor(s12, off);
    }
    float n1 = fmaxf(sqrtf(s1), 1e-12f);
    float n2 = fmaxf(sqrtf(s2), 1e-12f);
    float i1 = SCALE / n1;
    float i2 = SCALE / n2;

    int row1 = b, row2 = b + BATCH;
    size_t a1 = (size_t)(row1 >> 4) * 2048 + (row1 & 15) * 8;
    size_t a2 = (size_t)(row2 >> 4) * 2048 + (row2 & 15) * 8;
    int c0 = (l >> 3) * 128 + (l & 7);      // k = l
    int c1 = c0 + 8 * 128;                  // k = l + 64
    repsL[a1 + c0] = (bf16)(x0 * i1);
    repsL[a1 + c1] = (bf16)(x1 * i1);
    repsL[a2 + c0] = (bf16)(y0 * i2);
    repsL[a2 + c1] = (bf16)(y1 * i2);

    if (l == 0) {
        pos[b] = s12 / (n1 * n2);           // exact fp32 positive (unscaled)
        if (b == 0) out[0] = 0.0f;
    }
}

// Kernel 2: 128x128 pair-region per block, triangular TM<=TN (grid 65x32 = 2080
// blocks, zero idle). 4 waves in 2x2: wave (wm,wn) owns 64x64 tile pair
// (tm,tn) = (2TM+wm, 2TN+wn), tm<=tn; mirror quadrant of diag region skipped.
// Co-resident waves share each A/B 64-tile 2x via L1. Fragments are
// ks-streamed with a double buffer (64 frag VGPRs, not 128) for occupancy.
// Single MFMA pass; row-sums via 4-level 16-lane butterfly (verified R3),
// col-sums in-lane + 2 shfl (verified R5). No LDS, no barriers, no atomics:
// part[k][r] written exactly once (k>=j by row-parts of (j,k), k<j by
// col-parts of (k,j), k==j by the diag tile's row-part).
__global__ __launch_bounds__(256) void sim_kernel(const bf16* __restrict__ repsL,
                                                  float* __restrict__ part) {
    int tid = threadIdx.x;
    int wid = tid >> 6, lane = tid & 63;
    int wm = wid >> 1, wn = wid & 1;
    int lr = lane & 15, q = lane >> 4;
    int r = blockIdx.y;                  // [0,32)
    int c = blockIdx.x;                  // [0,65)
    int TM, TN;
    if (c < 64 - r) { TM = r;      TN = r + c; }
    else            { TM = 63 - r; TN = TM + (c - (64 - r)); }
    if (TM == TN && wm == 1 && wn == 0) return;   // mirror quadrant
    int tm = 2 * TM + wm, tn = 2 * TN + wn;       // tm <= tn guaranteed
    bool diag = (tm == tn);

    const char* base = (const char*)repsL;
    int lofs = q * 256 + lr * 16;
    const char* ab = base + tm * 16384 + lofs;
    const char* bb = base + tn * 16384 + lofs;

    bf16x8 aA[4], bA[4], aB[4], bB[4];
    floatx4 acc[4][4] = {};

    #define LOADF(A, B, ks)                                              \
        { _Pragma("unroll")                                              \
          for (int mi = 0; mi < 4; ++mi)                                 \
              A[mi] = *(const bf16x8*)(ab + mi * 4096 + (ks) * 1024);    \
          _Pragma("unroll")                                              \
          for (int ni = 0; ni < 4; ++ni)                                 \
              B[ni] = *(const bf16x8*)(bb + ni * 4096 + (ks) * 1024); }
    #define MFMAS(A, B)                                                  \
        { _Pragma("unroll")                                              \
          for (int mi = 0; mi < 4; ++mi)                                 \
              _Pragma("unroll")                                          \
              for (int ni = 0; ni < 4; ++ni)                             \
                  acc[mi][ni] = __builtin_amdgcn_mfma_f32_16x16x32_bf16( \
                      A[mi], B[ni], acc[mi][ni], 0, 0, 0); }

    LOADF(aA, bA, 0)
    LOADF(aB, bB, 1)
    MFMAS(aA, bA)
    LOADF(aA, bA, 2)
    MFMAS(aB, bB)
    LOADF(aB, bB, 3)
    MFMAS(aA, bA)
    MFMAS(aB, bB)
    #undef LOADF
    #undef MFMAS

    // Epilogue. C/D layout: col = lr + 16*ni, row = q*4 + reg + 16*mi.
    float rp[4][4];
    float cs[4] = {0.0f, 0.0f, 0.0f, 0.0f};
    #pragma unroll
    for (int mi = 0; mi < 4; ++mi) {
        #pragma unroll
        for (int reg = 0; reg < 4; ++reg) {
            float rsum = 0.0f;
            #pragma unroll
            for (int ni = 0; ni < 4; ++ni) {
                float e = __expf(acc[mi][ni][reg]);       // native mul+exp
                if (diag && mi == ni && (q * 4 + reg) == lr) e = 0.0f;
                rsum += e;
                cs[ni] += e;
            }
            rp[mi][reg] = rsum;
        }
    }
    // Row sums: butterfly over the 16 lr-lanes (16 independent chains).
    #pragma unroll
    for (int mask = 1; mask < 16; mask <<= 1)
        #pragma unroll
        for (int mi = 0; mi < 4; ++mi)
            #pragma unroll
            for (int reg = 0; reg < 4; ++reg)
                rp[mi][reg] += __shfl_xor(rp[mi][reg], mask);
    if (lr == 0) {
        #pragma unroll
        for (int mi = 0; mi < 4; ++mi)
            #pragma unroll
            for (int reg = 0; reg < 4; ++reg)
                part[(size_t)tn * TWO_B + tm * 64 + mi * 16 + q * 4 + reg] =
                    rp[mi][reg];
    }
    if (!diag) {
        #pragma unroll
        for (int ni = 0; ni < 4; ++ni) {
            cs[ni] += __shfl_xor(cs[ni], 16);
            cs[ni] += __shfl_xor(cs[ni], 32);
        }
        if (q == 0) {
            #pragma unroll
            for (int ni = 0; ni < 4; ++ni)
                part[(size_t)tm * TWO_B + tn * 64 + ni * 16 + lr] = cs[ni];
        }
    }
}

// Kernel 3: denom[r] = sum_k part[k][r]; loss = mean(log(denom) - 2*pos).
__global__ __launch_bounds__(256) void reduce_kernel(const float* __restrict__ part,
                                                     const float* __restrict__ pos,
                                                     float* __restrict__ out) {
    int tid = threadIdx.x;
    int rr = blockIdx.x * 256 + tid;
    float s = 0.0f;
    #pragma unroll 8
    for (int k = 0; k < 128; ++k)
        s += part[(size_t)k * TWO_B + rr];
    float v = __logf(s) - 2.0f * pos[rr & (BATCH - 1)];
    #pragma unroll
    for (int off = 32; off; off >>= 1) v += __shfl_xor(v, off);
    __shared__ float sred[4];
    int lane = tid & 63, wid = tid >> 6;
    if (lane == 0) sred[wid] = v;
    __syncthreads();
    if (tid == 0)
        atomicAdd(out, (sred[0] + sred[1] + sred[2] + sred[3]) * (1.0f / TWO_B));
}

extern "C" void kernel_launch(void* const* d_in, const int* in_sizes, int n_in,
                              void* d_out, int out_size, void* d_ws, size_t ws_size,
                              hipStream_t stream) {
    const float* p1 = (const float*)d_in[0];
    const float* p2 = (const float*)d_in[1];
    float* out = (float*)d_out;

    char* ws = (char*)d_ws;
    bf16* repsL = (bf16*)ws;                                          // 2 MB
    float* pos = (float*)(ws + (size_t)TWO_B * DIM * sizeof(bf16));   // 16 KB
    float* part = pos + BATCH;                                        // 4 MB

    norm_kernel<<<BATCH / 4, 256, 0, stream>>>(p1, p2, repsL, pos, out);
    sim_kernel<<<dim3(65, 32), 256, 0, stream>>>(repsL, part);
    reduce_kernel<<<TWO_B / 256, 256, 0, stream>>>(part, pos, out);
}

// Round 7
// 88.600 us; speedup vs baseline: 1.0826x; 1.0013x over previous
//
#include <hip/hip_runtime.h>
#include <hip/hip_bf16.h>
#include <math.h>

#define BATCH 4096
#define DIM 128
#define TWO_B 8192
// reps scaled by sqrt(2*log2(e)) so fp8 MFMA acc = 2*log2(e)*sim, and
// exp(sim/TEMP) = exp(2*sim) = exp2(acc) -> single native v_exp_f32.
#define SCALE 1.69864374f

typedef float floatx4 __attribute__((ext_vector_type(4)));
typedef int   intx4  __attribute__((ext_vector_type(4)));
typedef long  longx2 __attribute__((ext_vector_type(2)));

__device__ __forceinline__ longx2 as_l2(intx4 v) {
    union { intx4 a; longx2 b; } u; u.a = v; return u.b;
}
__device__ __forceinline__ unsigned char to_fp8(float v) {
    return (unsigned char)(__builtin_amdgcn_cvt_pk_fp8_f32(v, v, 0, false) & 0xff);
}

// FP8 fragment-native blocked layout (byte address):
//   addr(r,k) = (r>>4)*2048 + (k>>6)*1024 + ((k>>3)&3)*256 + (r&15)*16
//             + ((k>>5)&1)*8 + (k&7)
// A wave's 16-lane-group load at  q*256 + lr*16  of 16B yields, per lane,
// bytes {k=64h+8q+j | j<8} (chunk 2h) and {k=64h+32+8q+j} (chunk 2h+1):
// exactly the mfma_f32_16x16x32_fp8 A/B fragments for two K=32 chunks,
// fully coalesced (1KB/instruction). Total reps = 1MB -> L2-resident.

// Kernel 1: L2-normalize (pre-scaled) -> fp8 blocked reps; fp32 positives.
__global__ __launch_bounds__(256) void norm_kernel(const float* __restrict__ p1,
                                                   const float* __restrict__ p2,
                                                   unsigned char* __restrict__ repsF,
                                                   float* __restrict__ pos,
                                                   float* __restrict__ out) {
    int tid = threadIdx.x;
    int w = tid >> 6, l = tid & 63;
    int b = blockIdx.x * 4 + w;
    const float* r1 = p1 + (size_t)b * DIM;
    const float* r2 = p2 + (size_t)b * DIM;
    float x0 = r1[l], x1 = r1[l + 64];
    float y0 = r2[l], y1 = r2[l + 64];
    float s1 = x0 * x0 + x1 * x1;
    float s2 = y0 * y0 + y1 * y1;
    float s12 = x0 * y0 + x1 * y1;
    #pragma unroll
    for (int off = 32; off; off >>= 1) {
        s1  += __shfl_xor(s1, off);
        s2  += __shfl_xor(s2, off);
        s12 += __shfl_xor(s12, off);
    }
    float n1 = fmaxf(sqrtf(s1), 1e-12f);
    float n2 = fmaxf(sqrtf(s2), 1e-12f);
    float i1 = SCALE / n1;
    float i2 = SCALE / n2;

    int r1i = b, r2i = b + BATCH;
    int off0 = ((l >> 5) & 1) * 8 + ((l >> 3) & 3) * 256 + (l & 7);  // k = l (h=0)
    size_t a1 = (size_t)(r1i >> 4) * 2048 + (r1i & 15) * 16 + off0;
    size_t a2 = (size_t)(r2i >> 4) * 2048 + (r2i & 15) * 16 + off0;
    repsF[a1]        = to_fp8(x0 * i1);      // k = l
    repsF[a1 + 1024] = to_fp8(x1 * i1);      // k = l + 64 (h=1)
    repsF[a2]        = to_fp8(y0 * i2);
    repsF[a2 + 1024] = to_fp8(y1 * i2);

    if (l == 0) {
        pos[b] = s12 / (n1 * n2);            // exact fp32 positive (unscaled)
        if (b == 0) out[0] = 0.0f;
    }
}

// Kernel 2: 128x128 pair-region per block, triangular TM<=TN (grid 65x32,
// zero idle). 4 waves 2x2; wave (wm,wn) owns 64x64 tile pair (tm<=tn);
// mirror quadrant of diag region skipped. All-K fp8 fragments resident
// (16x dwordx4 up-front, ~64 VGPR), single MFMA pass, bare-exp2 epilogue.
// No LDS, no barriers, no atomics: part[k][r] written exactly once
// (k>=j row-parts of (j,k); k<j col-parts of (k,j); k==j diag row-part).
__global__ __launch_bounds__(256, 3) void sim_kernel(const unsigned char* __restrict__ repsF,
                                                     float* __restrict__ part) {
    int tid = threadIdx.x;
    int wid = tid >> 6, lane = tid & 63;
    int wm = wid >> 1, wn = wid & 1;
    int lr = lane & 15, q = lane >> 4;
    int r = blockIdx.y;                  // [0,32)
    int c = blockIdx.x;                  // [0,65)
    int TM, TN;
    if (c < 64 - r) { TM = r;      TN = r + c; }
    else            { TM = 63 - r; TN = TM + (c - (64 - r)); }
    if (TM == TN && wm == 1 && wn == 0) return;   // mirror quadrant
    int tm = 2 * TM + wm, tn = 2 * TN + wn;       // tm <= tn guaranteed
    bool diag = (tm == tn);

    const char* base = (const char*)repsF;
    int lofs = q * 256 + lr * 16;
    const char* ab = base + tm * 8192 + lofs;
    const char* bb = base + tn * 8192 + lofs;

    longx2 aF[4][2], bF[4][2];           // [mi][h]: .x = chunk 2h, .y = 2h+1
    #pragma unroll
    for (int mi = 0; mi < 4; ++mi)
        #pragma unroll
        for (int h = 0; h < 2; ++h) {
            aF[mi][h] = as_l2(*(const intx4*)(ab + mi * 2048 + h * 1024));
            bF[mi][h] = as_l2(*(const intx4*)(bb + mi * 2048 + h * 1024));
        }

    floatx4 acc[4][4] = {};
    #pragma unroll
    for (int ck = 0; ck < 4; ++ck) {     // K=32 chunks
        int h = ck >> 1, sel = ck & 1;
        #pragma unroll
        for (int mi = 0; mi < 4; ++mi)
            #pragma unroll
            for (int ni = 0; ni < 4; ++ni)
                acc[mi][ni] = __builtin_amdgcn_mfma_f32_16x16x32_fp8_fp8(
                    aF[mi][h][sel], bF[ni][h][sel], acc[mi][ni], 0, 0, 0);
    }

    // Epilogue. C/D layout: col = lr + 16*ni, row = q*4 + reg + 16*mi.
    float cs[4] = {0.0f, 0.0f, 0.0f, 0.0f};
    #pragma unroll
    for (int mi = 0; mi < 4; ++mi) {
        float rp[4];
        #pragma unroll
        for (int reg = 0; reg < 4; ++reg) {
            float e0 = __builtin_amdgcn_exp2f(acc[mi][0][reg]);
            float e1 = __builtin_amdgcn_exp2f(acc[mi][1][reg]);
            float e2 = __builtin_amdgcn_exp2f(acc[mi][2][reg]);
            float e3 = __builtin_amdgcn_exp2f(acc[mi][3][reg]);
            if (diag && (q * 4 + reg) == lr) {
                if (mi == 0) e0 = 0.0f;
                if (mi == 1) e1 = 0.0f;
                if (mi == 2) e2 = 0.0f;
                if (mi == 3) e3 = 0.0f;
            }
            cs[0] += e0; cs[1] += e1; cs[2] += e2; cs[3] += e3;
            rp[reg] = (e0 + e1) + (e2 + e3);
        }
        #pragma unroll
        for (int mask = 1; mask < 16; mask <<= 1)
            #pragma unroll
            for (int reg = 0; reg < 4; ++reg)
                rp[reg] += __shfl_xor(rp[reg], mask);
        if (lr == 0) {
            #pragma unroll
            for (int reg = 0; reg < 4; ++reg)
                part[(size_t)tn * TWO_B + tm * 64 + mi * 16 + q * 4 + reg] = rp[reg];
        }
    }
    if (!diag) {
        #pragma unroll
        for (int ni = 0; ni < 4; ++ni) {
            cs[ni] += __shfl_xor(cs[ni], 16);
            cs[ni] += __shfl_xor(cs[ni], 32);
        }
        if (q == 0) {
            #pragma unroll
            for (int ni = 0; ni < 4; ++ni)
                part[(size_t)tm * TWO_B + tn * 64 + ni * 16 + lr] = cs[ni];
        }
    }
}

// Kernel 3: denom[r] = sum_k part[k][r]; loss = mean(log(denom) - 2*pos).
__global__ __launch_bounds__(128) void reduce_kernel(const float* __restrict__ part,
                                                     const float* __restrict__ pos,
                                                     float* __restrict__ out) {
    int tid = threadIdx.x;
    int rr = blockIdx.x * 128 + tid;
    float s0 = 0.0f, s1 = 0.0f, s2 = 0.0f, s3 = 0.0f;
    #pragma unroll 8
    for (int k = 0; k < 128; k += 4) {
        s0 += part[(size_t)(k + 0) * TWO_B + rr];
        s1 += part[(size_t)(k + 1) * TWO_B + rr];
        s2 += part[(size_t)(k + 2) * TWO_B + rr];
        s3 += part[(size_t)(k + 3) * TWO_B + rr];
    }
    float v = __logf((s0 + s1) + (s2 + s3)) - 2.0f * pos[rr & (BATCH - 1)];
    #pragma unroll
    for (int off = 32; off; off >>= 1) v += __shfl_xor(v, off);
    __shared__ float sred[2];
    int lane = tid & 63, wid = tid >> 6;
    if (lane == 0) sred[wid] = v;
    __syncthreads();
    if (tid == 0)
        atomicAdd(out, (sred[0] + sred[1]) * (1.0f / TWO_B));
}

extern "C" void kernel_launch(void* const* d_in, const int* in_sizes, int n_in,
                              void* d_out, int out_size, void* d_ws, size_t ws_size,
                              hipStream_t stream) {
    const float* p1 = (const float*)d_in[0];
    const float* p2 = (const float*)d_in[1];
    float* out = (float*)d_out;

    char* ws = (char*)d_ws;
    unsigned char* repsF = (unsigned char*)ws;                 // 1 MB
    float* pos  = (float*)(ws + (size_t)TWO_B * DIM);          // 16 KB
    float* part = pos + BATCH;                                 // 4 MB

    norm_kernel<<<BATCH / 4, 256, 0, stream>>>(p1, p2, repsF, pos, out);
    sim_kernel<<<dim3(65, 32), 256, 0, stream>>>(repsF, part);
    reduce_kernel<<<TWO_B / 128, 128, 0, stream>>>(part, pos, out);
}